// Round 1
// baseline (69.018 us; speedup 1.0000x reference)
//
#include <hip/hip_runtime.h>

#define MOM 0.9f

// Kernel 1: per-row argmax of scores (first-max tie-break, matching np.argmax),
// emit key[i] = (label << 1) | (pred != label)
__global__ __launch_bounds__(256) void argmax_key_kernel(
    const float* __restrict__ scores, const int* __restrict__ labels,
    int* __restrict__ key, int C)
{
    const int row = blockIdx.x;
    const float* rp = scores + (size_t)row * C;
    float best = -__builtin_inff();
    int bidx = 0x7fffffff;

    const int nv = C >> 2;
    const float4* r4 = (const float4*)rp;
    for (int v = threadIdx.x; v < nv; v += 256) {
        float4 s = r4[v];
        int b = v << 2;
        // strict > keeps the FIRST max within this thread's ascending sequence
        if (s.x > best) { best = s.x; bidx = b; }
        if (s.y > best) { best = s.y; bidx = b + 1; }
        if (s.z > best) { best = s.z; bidx = b + 2; }
        if (s.w > best) { best = s.w; bidx = b + 3; }
    }
    for (int c = (nv << 2) + threadIdx.x; c < C; c += 256) {
        float s = rp[c];
        if (s > best) { best = s; bidx = c; }
    }

    __shared__ float sv[256];
    __shared__ int   si[256];
    sv[threadIdx.x] = best;
    si[threadIdx.x] = bidx;
    __syncthreads();
    for (int off = 128; off > 0; off >>= 1) {
        if (threadIdx.x < off) {
            float ov = sv[threadIdx.x + off];
            int   oi = si[threadIdx.x + off];
            float cv = sv[threadIdx.x];
            int   ci = si[threadIdx.x];
            if (ov > cv || (ov == cv && oi < ci)) {
                sv[threadIdx.x] = ov;
                si[threadIdx.x] = oi;
            }
        }
        __syncthreads();
    }
    if (threadIdx.x == 0) {
        int lab = labels[row];
        key[row] = (lab << 1) | ((si[0] != lab) ? 1 : 0);
    }
}

// Kernel 2: one block per class l.
// Collect (sorted ascending, deterministically via wave ballot) the chosen
// samples with label l, then:
//   new_bank[l] = m^k * bank[l] + sum_p (1-m)*m^(k-1-p) * feat[j_p]
//   new_times[l] = times[l] + k
__global__ __launch_bounds__(256) void class_update_kernel(
    const float* __restrict__ bank, const float* __restrict__ times,
    const float* __restrict__ feat, const int* __restrict__ key,
    float* __restrict__ out_bank, float* __restrict__ out_times,
    int B, int D)
{
    const int l = blockIdx.x;
    const int tid = threadIdx.x;
    __shared__ unsigned short midx[4096];  // 8 KB, worst-case all samples match
    __shared__ int wavecnt[4];

    const int target = (l << 1) | 1;
    const int lane = tid & 63;
    const int wid  = tid >> 6;

    int base = 0;
    const int rounds = (B + 255) >> 8;
    for (int it = 0; it < rounds; ++it) {
        int j = tid + (it << 8);
        bool match = (j < B) && (key[j] == target);
        unsigned long long m = __ballot(match);
        if (lane == 0) wavecnt[wid] = __popcll(m);
        __syncthreads();
        int woff = 0, tot = 0;
#pragma unroll
        for (int w = 0; w < 4; ++w) {
            int c = wavecnt[w];
            if (w < wid) woff += c;
            tot += c;
        }
        if (match) {
            int pos = base + woff + __popcll(m & ((1ull << lane) - 1ull));
            midx[pos] = (unsigned short)j;
        }
        base += tot;
        __syncthreads();
    }
    const int k = base;

    const float scale = powf(MOM, (float)k);
    const float one_minus_m = 1.0f - MOM;

    const int nv = D >> 2;
    const float4* brow = (const float4*)(bank + (size_t)l * D);
    float4* orow = (float4*)(out_bank + (size_t)l * D);
    for (int v = tid; v < nv; v += 256) {
        float4 a = brow[v];
        a.x *= scale; a.y *= scale; a.z *= scale; a.w *= scale;
        for (int p = 0; p < k; ++p) {
            int j = midx[p];
            float wgt = one_minus_m * powf(MOM, (float)(k - 1 - p));
            const float4* f4 = (const float4*)(feat + (size_t)j * D);
            float4 f = f4[v];
            a.x += wgt * f.x;
            a.y += wgt * f.y;
            a.z += wgt * f.z;
            a.w += wgt * f.w;
        }
        orow[v] = a;
    }
    if (tid == 0) out_times[l] = times[l] + (float)k;
}

extern "C" void kernel_launch(void* const* d_in, const int* in_sizes, int n_in,
                              void* d_out, int out_size, void* d_ws, size_t ws_size,
                              hipStream_t stream) {
    const float* scores = (const float*)d_in[0];
    const float* feat   = (const float*)d_in[1];
    const float* bank   = (const float*)d_in[2];
    const float* times  = (const float*)d_in[3];
    const int*   labels = (const int*)d_in[4];

    const int B = in_sizes[4];            // 4096
    const int C = in_sizes[3];            // 10000
    const int D = in_sizes[1] / B;        // 1024

    float* out_bank  = (float*)d_out;
    float* out_times = out_bank + (size_t)C * D;

    int* key = (int*)d_ws;                // B ints

    argmax_key_kernel<<<B, 256, 0, stream>>>(scores, labels, key, C);
    class_update_kernel<<<C, 256, 0, stream>>>(bank, times, feat, key,
                                               out_bank, out_times, B, D);
}